// Round 7
// baseline (354.211 us; speedup 1.0000x reference)
//
#include <hip/hip_runtime.h>

#define NN 100000
#define NE 1600000
#define HD 128
#define NB 391          // coarse buckets of 256 target nodes (tgt>>8)
#define CAP 64          // per-node LDS list capacity; deg~Poisson(16)
#define EPB 2048        // edges per histogram/partition block (4/thread)

typedef __attribute__((ext_vector_type(8))) short short8;   // 8 bf16
typedef __attribute__((ext_vector_type(4))) float v4f;
union U8 { uint4 u; short8 s; };

__device__ inline unsigned pk2(float a, float b) {          // 2x f32 -> packed bf16 (RNE)
  unsigned ua = __float_as_uint(a), ub = __float_as_uint(b);
  ua = (ua + 0x7fffu + ((ua >> 16) & 1u)) >> 16;
  ub = (ub + 0x7fffu + ((ub >> 16) & 1u)) >> 16;
  return ua | (ub << 16);
}
__device__ inline float blo(unsigned h) { return __uint_as_float(h << 16); }
__device__ inline float bhi(unsigned h) { return __uint_as_float(h & 0xffff0000u); }

// ---- fp32 -> bf16 bulk convert (8 elems/thread) -----------------------------
__global__ __launch_bounds__(256) void cvt_bf16(
    const float* __restrict__ src, unsigned short* __restrict__ dst, int n8)
{
  int i = blockIdx.x * 256 + threadIdx.x;
  if (i >= n8) return;
  const float4* s = (const float4*)src + (size_t)i * 2;
  float4 a = s[0], b = s[1];
  uint4 o;
  o.x = pk2(a.x, a.y); o.y = pk2(a.z, a.w);
  o.z = pk2(b.x, b.y); o.w = pk2(b.z, b.w);
  ((uint4*)dst)[i] = o;
}

// ---- weights cvt + meta zero in one launch (grid 21) ------------------------
__global__ __launch_bounds__(256) void cvt_weights(
    const float* __restrict__ W, const float* __restrict__ phi,
    const float* __restrict__ pred,
    unsigned short* __restrict__ Wb, unsigned short* __restrict__ phib,
    unsigned short* __restrict__ predb, unsigned* __restrict__ meta)
{
  if (blockIdx.x == 20) {                   // meta zero block
    for (int j = threadIdx.x; j < NB; j += 256) meta[j] = 0;
    if (threadIdx.x == 0) meta[1536] = 0;
    return;
  }
  int i = blockIdx.x * 256 + threadIdx.x;   // 5120 units of 8 elems
  const float* s; unsigned short* d; int j;
  if (i < 2048)      { s = W;    d = Wb;    j = i; }
  else if (i < 4096) { s = phi;  d = phib;  j = i - 2048; }
  else               { s = pred; d = predb; j = i - 4096; }
  const float4* sp = (const float4*)s + (size_t)j * 2;
  float4 a = sp[0], b = sp[1];
  uint4 o;
  o.x = pk2(a.x, a.y); o.y = pk2(a.z, a.w);
  o.z = pk2(b.x, b.y); o.w = pk2(b.z, b.w);
  ((uint4*)d)[j] = o;
}

// meta layout (u32): [0..NB) bhist | [512..512+NB) base | [1024..1024+NB) gcur
//                    | [1536] oflw_cnt
__global__ __launch_bounds__(512) void k_hist(
    const int* __restrict__ ei, unsigned* __restrict__ meta)
{
  __shared__ unsigned lh[NB];
  const int t = threadIdx.x;
  for (int i = t; i < NB; i += 512) lh[i] = 0;
  __syncthreads();
#pragma unroll
  for (int j = 0; j < 4; j++) {
    int e = blockIdx.x * EPB + j * 512 + t;
    if (e < NE) {
      unsigned tgt = (unsigned)ei[NE + e];
      atomicAdd(&lh[tgt >> 8], 1u);
    }
  }
  __syncthreads();
  for (int i = t; i < NB; i += 512)
    if (lh[i]) atomicAdd(&meta[i], lh[i]);
}

__global__ __launch_bounds__(512) void k_scan(unsigned* __restrict__ meta) {
  __shared__ unsigned sc[512];
  const int t = threadIdx.x;
  unsigned v = (t < NB) ? meta[t] : 0u;
  sc[t] = v;
  for (int off = 1; off < 512; off <<= 1) {
    __syncthreads();
    unsigned w = (t >= off) ? sc[t - off] : 0u;
    __syncthreads();
    sc[t] += w;
  }
  unsigned excl = sc[t] - v;
  if (t < NB) { meta[512 + t] = excl; meta[1024 + t] = excl; }
}

// Partition edges into bucket-contiguous runs with coalesced writes.
__global__ __launch_bounds__(512) void k_part(
    const int* __restrict__ ei, unsigned* __restrict__ meta,
    unsigned* __restrict__ edge_part)
{
  __shared__ unsigned lh[512], sc[512], lb[512], gb[512], lcur[512];
  __shared__ unsigned staged[EPB], sgo[EPB];
  __shared__ unsigned tot;
  const int t = threadIdx.x;
  lh[t] = 0;
  __syncthreads();

  unsigned rec[4]; short bb[4];
#pragma unroll
  for (int j = 0; j < 4; j++) {
    int e = blockIdx.x * EPB + j * 512 + t;
    if (e < NE) {
      unsigned tgt = (unsigned)ei[NE + e];
      unsigned src = (unsigned)ei[e];
      unsigned b = tgt >> 8;
      rec[j] = ((tgt & 255u) << 17) | src;
      bb[j] = (short)b;
      atomicAdd(&lh[b], 1u);
    } else bb[j] = -1;
  }
  __syncthreads();

  unsigned v = lh[t];
  sc[t] = v;
  for (int off = 1; off < 512; off <<= 1) {
    __syncthreads();
    unsigned w = (t >= off) ? sc[t - off] : 0u;
    __syncthreads();
    sc[t] += w;
  }
  lb[t] = sc[t] - v;
  lcur[t] = lb[t];
  if (t == 511) tot = sc[511];
  gb[t] = (t < NB && v) ? atomicAdd(&meta[1024 + t], v) : 0u;
  __syncthreads();

#pragma unroll
  for (int j = 0; j < 4; j++) {
    if (bb[j] >= 0) {
      unsigned b = (unsigned)bb[j];
      unsigned o = atomicAdd(&lcur[b], 1u);
      staged[o] = rec[j];
      sgo[o] = gb[b] + (o - lb[b]);
    }
  }
  __syncthreads();
  unsigned T = tot;
#pragma unroll
  for (int j = 0; j < 4; j++) {
    unsigned idx = j * 512 + t;
    if (idx < T) edge_part[sgo[idx]] = staged[idx];
  }
}

// One block per EIGHTH bucket (32 nodes): bin this eighth's edges into
// per-node LDS lists, then gather x rows with 16-lane uint4 groups.
__global__ __launch_bounds__(512) void k_gather(
    const unsigned* __restrict__ edge_part, const unsigned* __restrict__ meta,
    const uint4* __restrict__ xb4,          // xb as uint4 (16 B = 8 bf16)
    unsigned* __restrict__ aggbu,           // [NN][64] u32 (bf16 pairs)
    float* __restrict__ degf,
    unsigned* __restrict__ oflw, unsigned* __restrict__ meta_oflw)
{
  __shared__ unsigned cnt[32];
  __shared__ unsigned list[32 * CAP];       // 8 KB
  const int t = threadIdx.x;
  const unsigned b = blockIdx.x >> 3;       // coarse bucket
  const unsigned q = blockIdx.x & 7;        // eighth within bucket
  const unsigned nbase = (b << 8) + (q << 5);
  const unsigned ebase = meta[512 + b];
  const unsigned ecnt  = meta[b];
  if (t < 32) cnt[t] = 0;
  __syncthreads();

  for (unsigned k = t; k < ecnt; k += 512) {
    unsigned rec = edge_part[ebase + k];
    unsigned tl = rec >> 17;
    if ((tl >> 5) == q) {
      unsigned ql = tl & 31;
      unsigned src = rec & 0x1FFFFu;
      unsigned p = atomicAdd(&cnt[ql], 1u);
      if (p < CAP) list[ql * CAP + p] = src;
      else {
        unsigned op = atomicAdd(&meta_oflw[1536], 1u);
        oflw[op * 2] = nbase + ql;
        oflw[op * 2 + 1] = src;
      }
    }
  }
  __syncthreads();

  const int wave = t >> 6, lane = t & 63;
  const int g = lane >> 4, c = lane & 15;   // 4 edge-slots x 16 channel-quads
#pragma unroll
  for (int k = 0; k < 4; k++) {
    unsigned ql = wave * 4 + k;
    long n = (long)nbase + ql;
    if (n >= NN) continue;
    unsigned deg = cnt[ql];
    if (lane == 0) degf[n] = (float)deg;
    int d2 = deg < CAP ? (int)deg : CAP;
    float a[8] = {0, 0, 0, 0, 0, 0, 0, 0};
    for (int e = g; e < d2; e += 4) {        // 4 edges in flight per wave
      unsigned s = list[ql * CAP + e];       // broadcast within 16-lane group
      uint4 v = xb4[(size_t)s * 16 + c];     // 256 B contiguous per group
      a[0] += blo(v.x); a[1] += bhi(v.x);
      a[2] += blo(v.y); a[3] += bhi(v.y);
      a[4] += blo(v.z); a[5] += bhi(v.z);
      a[6] += blo(v.w); a[7] += bhi(v.w);
    }
#pragma unroll
    for (int m = 16; m <= 32; m <<= 1)
#pragma unroll
      for (int j = 0; j < 8; j++)
        a[j] += __shfl_xor(a[j], m, 64);
    if (g == 0) {
      uint4 o = make_uint4(pk2(a[0], a[1]), pk2(a[2], a[3]),
                           pk2(a[4], a[5]), pk2(a[6], a[7]));
      *(uint4*)&aggbu[n * 64 + c * 4] = o;
    }
  }
}

// Serial fix-up for deg>CAP spill edges (normally zero iterations).
__global__ __launch_bounds__(64) void k_oflow(
    const unsigned* __restrict__ meta, const unsigned* __restrict__ oflw,
    const float* __restrict__ x, unsigned* __restrict__ aggbu)
{
  const int t = threadIdx.x;
  unsigned m = meta[1536];
  for (unsigned i = 0; i < m; i++) {
    unsigned tgt = oflw[i * 2], src = oflw[i * 2 + 1];
    unsigned c = aggbu[(size_t)tgt * 64 + t];
    float a0 = blo(c) + x[(size_t)src * HD + t * 2];
    float a1 = bhi(c) + x[(size_t)src * HD + t * 2 + 1];
    aggbu[(size_t)tgt * 64 + t] = pk2(a0, a1);
  }
}

// Fused K=256 GEMM: x_new = relu(W@agg + deg*W_b + phi@u + phi_b), then
// pred head y = x_new @ pred^T + pred_b via swizzled LDS stage.
// 16 nodes/wave, 64 nodes/block, no cross-wave sync (xs is per-wave).
__global__ __launch_bounds__(256) void k_fused(
    const unsigned* __restrict__ aggbu,
    const float* __restrict__ u,
    const float* __restrict__ degf,
    const unsigned short* __restrict__ Wb,
    const unsigned short* __restrict__ phib,
    const unsigned short* __restrict__ predb,
    const float* __restrict__ W_b, const float* __restrict__ phi_b,
    const float* __restrict__ pred_b,
    float* __restrict__ out_x, float* __restrict__ out_y)
{
  __shared__ unsigned xs[4 * 16 * 64];      // 16 KB: per-wave x_new bf16, swizzled
  const int lane = threadIdx.x & 63;
  const int wv   = threadIdx.x >> 6;
  const long n0  = (long)blockIdx.x * 64 + wv * 16;
  const int r = lane & 15, h4 = lane >> 4;

  const long n = n0 + r;
  const long nc = (n < NN) ? n : 0;
  const float dg = degf[nc];

  U8 xf[4], uf[4];
  const unsigned* arow = aggbu + nc * 64 + h4 * 4;
  const float* urow = u + nc * HD + h4 * 8;
#pragma unroll
  for (int ks = 0; ks < 4; ks++) {
    xf[ks].u = *(const uint4*)(arow + ks * 16);
    float4 a = *(const float4*)(urow + ks * 32);
    float4 b = *(const float4*)(urow + ks * 32 + 4);
    uf[ks].u = make_uint4(pk2(a.x, a.y), pk2(a.z, a.w),
                          pk2(b.x, b.y), pk2(b.z, b.w));
  }

#pragma unroll
  for (int ct = 0; ct < 8; ct++) {
    const int c0 = ct * 16 + r;
    float4 wb4 = *(const float4*)&W_b[ct * 16 + h4 * 4];
    float4 pb4 = *(const float4*)&phi_b[ct * 16 + h4 * 4];
    v4f acc = (v4f){fmaf(dg, wb4.x, pb4.x), fmaf(dg, wb4.y, pb4.y),
                    fmaf(dg, wb4.z, pb4.z), fmaf(dg, wb4.w, pb4.w)};
#pragma unroll
    for (int ks = 0; ks < 4; ks++) {
      short8 wf = *(const short8*)&Wb[(size_t)c0 * HD + ks * 32 + h4 * 8];
      acc = __builtin_amdgcn_mfma_f32_16x16x32_bf16(wf, xf[ks].s, acc, 0, 0, 0);
    }
#pragma unroll
    for (int ks = 0; ks < 4; ks++) {
      short8 pf = *(const short8*)&phib[(size_t)c0 * HD + ks * 32 + h4 * 8];
      acc = __builtin_amdgcn_mfma_f32_16x16x32_bf16(pf, uf[ks].s, acc, 0, 0, 0);
    }
    float r0 = fmaxf(acc[0], 0.f), r1 = fmaxf(acc[1], 0.f);
    float r2 = fmaxf(acc[2], 0.f), r3 = fmaxf(acc[3], 0.f);
    if (n < NN)
      *(float4*)&out_x[n * HD + ct * 16 + h4 * 4] = make_float4(r0, r1, r2, r3);
    int chunk = ct * 2 + (h4 >> 1);
    unsigned* dst = &xs[(wv * 16 + r) * 64 + ((chunk ^ r) << 2) + ((h4 & 1) << 1)];
    *(uint2*)dst = make_uint2(pk2(r0, r1), pk2(r2, r3));
  }
  // no __syncthreads: each wave reads only its own xs rows; within-wave
  // ds_write -> ds_read ordering is enforced by lgkmcnt.

#pragma unroll
  for (int ct2 = 0; ct2 < 4; ct2++) {
    float4 qb4 = *(const float4*)&pred_b[ct2 * 16 + h4 * 4];
    v4f acc = (v4f){qb4.x, qb4.y, qb4.z, qb4.w};
#pragma unroll
    for (int ks = 0; ks < 4; ks++) {
      short8 pw = *(const short8*)&predb[(size_t)(ct2 * 16 + r) * HD + ks * 32 + h4 * 8];
      U8 bx;
      bx.u = *(const uint4*)&xs[(wv * 16 + r) * 64 + (((h4 + ks * 4) ^ r) << 2)];
      acc = __builtin_amdgcn_mfma_f32_16x16x32_bf16(pw, bx.s, acc, 0, 0, 0);
    }
    if (n < NN)
      *(float4*)&out_y[n * 64 + ct2 * 16 + h4 * 4] =
          make_float4(acc[0], acc[1], acc[2], acc[3]);
  }
}

// ---- fp32 fallback path (only if ws is too small) ---------------------------
template<int CT, int LDO, bool RELU_WB>
__global__ __launch_bounds__(256) void gemm_nodes(
    const float* __restrict__ in, float* in_wb,
    const float* __restrict__ Wg, const float* __restrict__ bias,
    float* __restrict__ out)
{
  __shared__ float Wt[HD * CT];
  __shared__ float xsh[32 * HD];
  const int tid = threadIdx.x;
  const int cbase = blockIdx.y * CT;
  for (int idx = tid; idx < HD * CT; idx += 256) {
    int c = idx >> 7, k = idx & 127;
    int chunk = ((c >> 1) ^ (k & 31));
    Wt[k * CT + (chunk << 1 | (c & 1))] = Wg[(size_t)(cbase + c) * HD + k];
  }
  const long nb = (long)blockIdx.x * 32;
  for (int idx = tid; idx < 32 * HD; idx += 256) {
    int n = idx >> 7, k = idx & 127;
    float v = in[(nb + n) * HD + k];
    if (RELU_WB) { v = fmaxf(v, 0.0f); in_wb[(nb + n) * HD + k] = v; }
    xsh[idx] = v;
  }
  __syncthreads();
  const int lane = tid & 31, grp = tid >> 5, c0 = lane * 2;
  float acc[4][2];
#pragma unroll
  for (int j = 0; j < 4; j++) { acc[j][0] = bias[cbase + c0]; acc[j][1] = bias[cbase + c0 + 1]; }
#pragma unroll 4
  for (int k = 0; k < HD; k += 4) {
    float xv[4][4];
#pragma unroll
    for (int j = 0; j < 4; j++) {
      float4 t = *(const float4*)&xsh[(grp * 4 + j) * HD + k];
      xv[j][0] = t.x; xv[j][1] = t.y; xv[j][2] = t.z; xv[j][3] = t.w;
    }
#pragma unroll
    for (int kk = 0; kk < 4; kk++) {
      int chunk = lane ^ ((k + kk) & 31);
      float2 w = *(const float2*)&Wt[(k + kk) * CT + (chunk << 1)];
#pragma unroll
      for (int j = 0; j < 4; j++) {
        acc[j][0] = fmaf(xv[j][kk], w.x, acc[j][0]);
        acc[j][1] = fmaf(xv[j][kk], w.y, acc[j][1]);
      }
    }
  }
#pragma unroll
  for (int j = 0; j < 4; j++) {
    long n = nb + grp * 4 + j;
    *(float2*)&out[n * LDO + c0 + cbase] = make_float2(acc[j][0], acc[j][1]);
  }
}

__global__ __launch_bounds__(256) void scatter_edges(
    const int* __restrict__ ei, const float* __restrict__ h, float* __restrict__ agg)
{
  const long t = (long)blockIdx.x * 256 + threadIdx.x;
  const int e = (int)(t >> 5), lane = (int)(t & 31);
  const int src = ei[e], tgt = ei[NE + e];
  const float4 v = *(const float4*)&h[(size_t)src * HD + lane * 4];
  float* dst = &agg[(size_t)tgt * HD + lane * 4];
  unsafeAtomicAdd(dst + 0, v.x); unsafeAtomicAdd(dst + 1, v.y);
  unsafeAtomicAdd(dst + 2, v.z); unsafeAtomicAdd(dst + 3, v.w);
}

// ---- launch -----------------------------------------------------------------
extern "C" void kernel_launch(void* const* d_in, const int* in_sizes, int n_in,
                              void* d_out, int out_size, void* d_ws, size_t ws_size,
                              hipStream_t stream) {
  const float* x      = (const float*)d_in[0];
  const float* u      = (const float*)d_in[1];
  const int*   ei     = (const int*)d_in[2];
  const float* W_w    = (const float*)d_in[3];
  const float* W_b    = (const float*)d_in[4];
  const float* phi_w  = (const float*)d_in[5];
  const float* phi_b  = (const float*)d_in[6];
  const float* pred_w = (const float*)d_in[7];
  const float* pred_b = (const float*)d_in[8];

  float* out_x = (float*)d_out;                       // [NN,128] x_new (f32)
  float* out_y = (float*)d_out + (size_t)NN * HD;     // [NN,64]  y (f32)

  // workspace layout (all 256B-aligned)
  char* p = (char*)d_ws;
  auto take = [&](size_t bytes) { char* r = p; p += (bytes + 255) & ~(size_t)255; return r; };
  unsigned short* xb  = (unsigned short*)take((size_t)NN * HD * 2);   // 25.6 MB
  unsigned* aggbu     = (unsigned*)take((size_t)NN * 64 * 4);         // 25.6 MB
  unsigned* edge_part = (unsigned*)take((size_t)NE * 4);              // 6.4 MB
  unsigned* oflw      = (unsigned*)take((size_t)NE * 8);              // 12.8 MB
  float* degf         = (float*)take((size_t)NN * 4);                 // 0.4 MB
  unsigned short* Wb    = (unsigned short*)take(16384 * 2);
  unsigned short* phib  = (unsigned short*)take(16384 * 2);
  unsigned short* predb = (unsigned short*)take(8192 * 2);
  unsigned* meta      = (unsigned*)take(2048 * 4);
  const size_t need = (size_t)(p - (char*)d_ws);

  dim3 b256(256), b512(512);
  if (ws_size >= need) {
    const int n8x = NN * HD / 8;                      // 1.6M
    cvt_bf16<<<dim3((n8x + 255) / 256), b256, 0, stream>>>(x, xb, n8x);
    cvt_weights<<<dim3(21), b256, 0, stream>>>(W_w, phi_w, pred_w, Wb, phib, predb, meta);
    k_hist<<<dim3((NE + EPB - 1) / EPB), b512, 0, stream>>>(ei, meta);
    k_scan<<<dim3(1), b512, 0, stream>>>(meta);
    k_part<<<dim3((NE + EPB - 1) / EPB), b512, 0, stream>>>(ei, meta, edge_part);
    k_gather<<<dim3(NB * 8), b512, 0, stream>>>(edge_part, meta, (const uint4*)xb,
                                                aggbu, degf, oflw, meta);
    k_oflow<<<dim3(1), dim3(64), 0, stream>>>(meta, oflw, x, aggbu);
    k_fused<<<dim3((NN + 63) / 64), b256, 0, stream>>>(
        aggbu, u, degf, Wb, phib, predb, W_b, phi_b, pred_b, out_x, out_y);
  } else {
    float* h = (float*)d_ws;
    gemm_nodes<64, 128, false><<<dim3(NN / 32, 2), b256, 0, stream>>>(x, nullptr, W_w, W_b, h);
    gemm_nodes<64, 128, false><<<dim3(NN / 32, 2), b256, 0, stream>>>(u, nullptr, phi_w, phi_b, out_x);
    scatter_edges<<<dim3((NE * 32) / 256), b256, 0, stream>>>(ei, h, out_x);
    gemm_nodes<64, 64, true><<<dim3(NN / 32, 1), b256, 0, stream>>>(out_x, out_x, pred_w, pred_b, out_y);
  }
}